// Round 18
// baseline (42.392 us; speedup 1.0000x reference)
//
#include <hip/hip_runtime.h>

#define NN   640
#define NW   20    // bitmask words per node (640/32)
#define H    64
#define MAXD 96    // degree cap; deg ~ Binomial(1279,.0187), mean 23.9

// SINGLE dispatch: block = node v, 512 threads = 8 waves.
// The whole edge list (3840 int4 quads per column) is register-prefetched ONCE
// (A[8]/B[8] per thread) and reused for BOTH passes:
//  P1: own-row scatter  (a==v)                    -> rowv (LDS)
//  P2: wave-0 shfl-scan enumeration               -> ulist/pre/deg
//  P4: triangle scatter (a,b both in N(v))        -> nb[pos(a)] |= bit(b)
//  P3: xa rows for u in N(v) in-block (3 matvecs/wave)
//  P5: all-LDS pair loop: h = relu(xa[u] + sum_S2 xa[w] + k0 + cnt*k1)
//  P6: tail on raw weights (r13-verified): agg = hsum@W1b + deg*b1b;
//      out = relu([x_v,0]+agg @ W0a + b0a) @ W0b + b0b
__global__ __launch_bounds__(512, 4) void rnp_solo(
    const int* __restrict__ ei, int E,
    const float* __restrict__ x,
    const float* __restrict__ W1a, const float* __restrict__ b1a,
    const float* __restrict__ W1b, const float* __restrict__ b1b,
    const float* __restrict__ W0a, const float* __restrict__ b0a,
    const float* __restrict__ W0b, const float* __restrict__ b0b,
    float* __restrict__ out)
{
    __shared__ __align__(16) unsigned rowv[NW];
    __shared__ __align__(16) unsigned nb[MAXD][NW];   // N(u) ∩ N(v) per neighbor
    __shared__ float xr[MAXD][H];                     // xa rows of N(v)
    __shared__ float p1[8][H];
    __shared__ float p2[8][H];
    __shared__ float p2b[8];
    __shared__ float ash[H];
    __shared__ unsigned short ulist[MAXD];
    __shared__ int pre[NW];
    __shared__ int s_deg;

    const int v = blockIdx.x, t = threadIdx.x;
    const int lane = t & 63, wave = t >> 6;

    if (t < NW) rowv[t] = 0u;
    for (int i = t; i < MAXD * NW; i += 512) ((unsigned*)nb)[i] = 0u;
    const float xvl = x[v * H + lane];                // own x row (used in tail)

    // ---- prefetch ALL edge quads once (one latency round, reused twice) ----
    const int quads = E >> 2;                         // 3840 for E=15360
    int4 A[8], B[8];
    #pragma unroll
    for (int i = 0; i < 8; ++i) {
        const int k = t + (i << 9);
        if (k < quads) {
            A[i] = ((const int4*)ei)[k];
            B[i] = ((const int4*)(ei + E))[k];
        }
    }
    __syncthreads();                                  // zeroing visible

    // ---- P1: own-row scatter from registers ----
    #pragma unroll
    for (int i = 0; i < 8; ++i) {
        const int k = t + (i << 9);
        if (k < quads) {
            if (A[i].x == v && B[i].x != v) atomicOr(&rowv[B[i].x >> 5], 1u << (B[i].x & 31));
            if (A[i].y == v && B[i].y != v) atomicOr(&rowv[B[i].y >> 5], 1u << (B[i].y & 31));
            if (A[i].z == v && B[i].z != v) atomicOr(&rowv[B[i].z >> 5], 1u << (B[i].z & 31));
            if (A[i].w == v && B[i].w != v) atomicOr(&rowv[B[i].w >> 5], 1u << (B[i].w & 31));
        }
    }
    for (int k = (quads << 2) + t; k < E; k += 512) { // generic remainder (empty here)
        const int a = ei[k], b = ei[k + E];
        if (a == v && b != v) atomicOr(&rowv[b >> 5], 1u << (b & 31));
    }
    __syncthreads();

    // ---- P2: neighbor enumeration (wave-0 shfl-scan prefix popcount) ----
    if (wave == 0) {
        unsigned word = (lane < NW) ? rowv[lane] : 0u;
        int pc = __popc(word), scan = pc;
        #pragma unroll
        for (int off = 1; off < 32; off <<= 1) {
            int nbv = __shfl_up(scan, off, 64);
            if (lane >= off) scan += nbv;
        }
        int o = scan - pc;                            // exclusive prefix
        if (lane < NW) pre[lane] = o;
        unsigned c = word;
        while (c) {
            int b = __ffs(c) - 1; c &= c - 1;
            if (o < MAXD) ulist[o] = (unsigned short)(lane * 32 + b);
            ++o;
        }
        if (lane == NW - 1) s_deg = (o < MAXD) ? o : MAXD;
    }
    __syncthreads();
    const int deg = s_deg;

    // ---- P4: triangle scatter FROM THE SAME REGISTERS (no new loads) ----
    #pragma unroll
    for (int i = 0; i < 8; ++i) {
        const int k = t + (i << 9);
        if (k < quads) {
            const int ax = A[i].x, bx = B[i].x;
            if (ax != bx && ((rowv[ax >> 5] >> (ax & 31)) & 1u)
                         && ((rowv[bx >> 5] >> (bx & 31)) & 1u)) {
                int pos = pre[ax >> 5] + __popc(rowv[ax >> 5] & ((1u << (ax & 31)) - 1));
                if (pos < MAXD) atomicOr(&nb[pos][bx >> 5], 1u << (bx & 31));
            }
            const int ay = A[i].y, by = B[i].y;
            if (ay != by && ((rowv[ay >> 5] >> (ay & 31)) & 1u)
                         && ((rowv[by >> 5] >> (by & 31)) & 1u)) {
                int pos = pre[ay >> 5] + __popc(rowv[ay >> 5] & ((1u << (ay & 31)) - 1));
                if (pos < MAXD) atomicOr(&nb[pos][by >> 5], 1u << (by & 31));
            }
            const int az = A[i].z, bz = B[i].z;
            if (az != bz && ((rowv[az >> 5] >> (az & 31)) & 1u)
                         && ((rowv[bz >> 5] >> (bz & 31)) & 1u)) {
                int pos = pre[az >> 5] + __popc(rowv[az >> 5] & ((1u << (az & 31)) - 1));
                if (pos < MAXD) atomicOr(&nb[pos][bz >> 5], 1u << (bz & 31));
            }
            const int aw = A[i].w, bw = B[i].w;
            if (aw != bw && ((rowv[aw >> 5] >> (aw & 31)) & 1u)
                         && ((rowv[bw >> 5] >> (bw & 31)) & 1u)) {
                int pos = pre[aw >> 5] + __popc(rowv[aw >> 5] & ((1u << (aw & 31)) - 1));
                if (pos < MAXD) atomicOr(&nb[pos][bw >> 5], 1u << (bw & 31));
            }
        }
    }
    for (int k = (quads << 2) + t; k < E; k += 512) { // generic remainder (empty here)
        const int a = ei[k], b = ei[k + E];
        if (a != b && ((rowv[a >> 5] >> (a & 31)) & 1u)
                   && ((rowv[b >> 5] >> (b & 31)) & 1u)) {
            int pos = pre[a >> 5] + __popc(rowv[a >> 5] & ((1u << (a & 31)) - 1));
            if (pos < MAXD) atomicOr(&nb[pos][b >> 5], 1u << (b & 31));
        }
    }

    // ---- P3: xa rows for N(v), in-block (3 matvecs/wave, 4-way ILP) ----
    for (int p = wave; p < deg; p += 8) {
        const int u = ulist[p];
        const float xu = x[u * H + lane];
        float a0 = 0, a1 = 0, a2 = 0, a3 = 0;
        #pragma unroll
        for (int k = 0; k < H; k += 4) {
            a0 += __shfl(xu, k, 64)     * W1a[k * H + lane];
            a1 += __shfl(xu, k + 1, 64) * W1a[(k + 1) * H + lane];
            a2 += __shfl(xu, k + 2, 64) * W1a[(k + 2) * H + lane];
            a3 += __shfl(xu, k + 3, 64) * W1a[(k + 3) * H + lane];
        }
        xr[p][lane] = (a0 + a1) + (a2 + a3);
    }
    __syncthreads();                                  // nb + xr ready

    // ---- P5: pair loop (all-LDS) ----
    const float r64v = W1a[64 * H + lane];
    const float k0 = b1a[lane] + r64v;                // b1a + 1*W1a[64]
    const float k1 = r64v + W1a[65 * H + lane];       // per-cnt term

    float hacc = 0.f;
    for (int p = wave; p < deg; p += 8) {
        const uint4* nbp = (const uint4*)nb[p];       // rows are 80B, 16B-aligned
        const uint4 q0 = nbp[0], q1 = nbp[1], q2 = nbp[2], q3 = nbp[3], q4 = nbp[4];
        unsigned cw[NW] = { q0.x, q0.y, q0.z, q0.w, q1.x, q1.y, q1.z, q1.w,
                            q2.x, q2.y, q2.z, q2.w, q3.x, q3.y, q3.z, q3.w,
                            q4.x, q4.y, q4.z, q4.w };
        int cnt = 0;
        #pragma unroll
        for (int j = 0; j < NW; ++j) cnt += __popc(cw[j]);
        float xs = 0.f;
        #pragma unroll
        for (int j = 0; j < NW; ++j) {
            unsigned c = cw[j];
            while (c) {
                int b = __ffs(c) - 1; c &= c - 1;
                int pos = pre[j] + __popc(rowv[j] & ((1u << b) - 1));
                xs += xr[pos][lane];                  // common-neighbor xa (LDS)
            }
        }
        float h = xr[p][lane] + xs + k0 + (float)cnt * k1;
        hacc += fmaxf(h, 0.f);                        // ReLU then accumulate
    }
    p1[wave][lane] = hacc;
    __syncthreads();

    // ---- P6: tail (r13-verified) ----
    float hs = 0.f;
    #pragma unroll
    for (int w = 0; w < 8; ++w) hs += p1[w][lane];    // full hsum, every wave

    float pa = 0.f, pa64 = 0.f;
    #pragma unroll
    for (int i = 0; i < 8; ++i) {
        const int d = wave * 8 + i;
        const float hd = __shfl(hs, d, 64);
        pa   += hd * W1b[d * 65 + lane];
        pa64 += hd * W1b[d * 65 + 64];
    }
    p2[wave][lane] = pa;
    if (lane == 0) p2b[wave] = pa64;
    __syncthreads();

    const float fdeg = (float)deg;
    float al  = fdeg * b1b[lane];
    float a64 = fdeg * b1b[64];
    #pragma unroll
    for (int w = 0; w < 8; ++w) { al += p2[w][lane]; a64 += p2b[w]; }
    if (wave == 0) ash[lane] = xvl + al;              // inp0[0..63]; inp0[64]=a64
    __syncthreads();

    float th = b0a[lane] + a64 * W0a[64 * H + lane];
    float t0 = 0, t1 = 0, t2 = 0, t3 = 0;
    #pragma unroll
    for (int k = 0; k < H; k += 4) {
        t0 += ash[k]     * W0a[k * H + lane];
        t1 += ash[k + 1] * W0a[(k + 1) * H + lane];
        t2 += ash[k + 2] * W0a[(k + 2) * H + lane];
        t3 += ash[k + 3] * W0a[(k + 3) * H + lane];
    }
    th = fmaxf(th + (t0 + t1) + (t2 + t3), 0.f);

    if (wave == 0) {
        float o0 = 0, o1 = 0, o2 = 0, o3 = 0;
        #pragma unroll
        for (int d = 0; d < H; d += 4) {
            o0 += __shfl(th, d, 64)     * W0b[d * H + lane];
            o1 += __shfl(th, d + 1, 64) * W0b[(d + 1) * H + lane];
            o2 += __shfl(th, d + 2, 64) * W0b[(d + 2) * H + lane];
            o3 += __shfl(th, d + 3, 64) * W0b[(d + 3) * H + lane];
        }
        out[v * H + lane] = b0b[lane] + (o0 + o1) + (o2 + o3);
    }
}

extern "C" void kernel_launch(void* const* d_in, const int* in_sizes, int n_in,
                              void* d_out, int out_size, void* d_ws, size_t ws_size,
                              hipStream_t stream) {
    const float* x   = (const float*)d_in[0];
    const float* W1a = (const float*)d_in[1];
    const float* b1a = (const float*)d_in[2];
    const float* W1b = (const float*)d_in[3];
    const float* b1b = (const float*)d_in[4];
    const float* W0a = (const float*)d_in[5];
    const float* b0a = (const float*)d_in[6];
    const float* W0b = (const float*)d_in[7];
    const float* b0b = (const float*)d_in[8];
    const int*   ei  = (const int*)d_in[9];
    const int    E   = in_sizes[9] / 2;

    rnp_solo<<<NN, 512, 0, stream>>>(ei, E, x, W1a, b1a, W1b, b1b,
                                     W0a, b0a, W0b, b0b, (float*)d_out);
}

// Round 19
// 20.552 us; speedup vs baseline: 2.0627x; 2.0627x over previous
//
#include <hip/hip_runtime.h>

#define NN   640
#define NW   20    // used bitmask words per node
#define NWP  24    // padded row stride in global (96 B -> 16B-aligned rows)
#define H    64
#define MAXD 96    // degree cap; deg ~ Binomial(1279,.0187), mean 23.9

// ---------------- K1: prep (champion r16) ----------------
// blocks 0..159 : 4 nodes each. Register-prefetched edge scan (one latency
//                 round), matvec per wave (4 nodes x {xa,xc}), then per-node
//                 neighbor-list enumeration -> ulg/degg (20-lane scan).
// blocks 160..167: Wf = W1b @ W0a. block 168: bf = b1b @ W0a.
__global__ __launch_bounds__(512) void prep(
    const int* __restrict__ ei, int E,
    const float* __restrict__ x,
    const float* __restrict__ W1a, const float* __restrict__ W0a,
    const float* __restrict__ W1b, const float* __restrict__ b1b,
    unsigned* __restrict__ bits, float* __restrict__ xa, float* __restrict__ xc,
    float* __restrict__ Wf, float* __restrict__ bf,
    unsigned short* __restrict__ ulg, int* __restrict__ degg)
{
    const int t = threadIdx.x, lane = t & 63, wave = t >> 6, bid = blockIdx.x;

    if (bid < 160) {
        __shared__ unsigned sb[4 * NW];
        if (t < 4 * NW) sb[t] = 0u;
        __syncthreads();

        const int quads = E >> 2;
        int4 A[8], B[8];
        #pragma unroll
        for (int i = 0; i < 8; ++i) {                   // prefetch: 16 indep loads
            const int k = t + (i << 9);
            if (k < quads) {
                A[i] = ((const int4*)ei)[k];
                B[i] = ((const int4*)(ei + E))[k];
            }
        }
        #pragma unroll
        for (int i = 0; i < 8; ++i) {                   // process from registers
            const int k = t + (i << 9);
            if (k < quads) {
                if ((A[i].x >> 2) == bid && A[i].x != B[i].x)
                    atomicOr(&sb[(A[i].x & 3) * NW + (B[i].x >> 5)], 1u << (B[i].x & 31));
                if ((A[i].y >> 2) == bid && A[i].y != B[i].y)
                    atomicOr(&sb[(A[i].y & 3) * NW + (B[i].y >> 5)], 1u << (B[i].y & 31));
                if ((A[i].z >> 2) == bid && A[i].z != B[i].z)
                    atomicOr(&sb[(A[i].z & 3) * NW + (B[i].z >> 5)], 1u << (B[i].z & 31));
                if ((A[i].w >> 2) == bid && A[i].w != B[i].w)
                    atomicOr(&sb[(A[i].w & 3) * NW + (B[i].w >> 5)], 1u << (B[i].w & 31));
            }
        }
        for (int k = t + (8 << 9); k < quads; k += 512) {   // generic overflow
            const int4 a4 = ((const int4*)ei)[k];
            const int4 b4 = ((const int4*)(ei + E))[k];
            if ((a4.x >> 2) == bid && a4.x != b4.x)
                atomicOr(&sb[(a4.x & 3) * NW + (b4.x >> 5)], 1u << (b4.x & 31));
            if ((a4.y >> 2) == bid && a4.y != b4.y)
                atomicOr(&sb[(a4.y & 3) * NW + (b4.y >> 5)], 1u << (b4.y & 31));
            if ((a4.z >> 2) == bid && a4.z != b4.z)
                atomicOr(&sb[(a4.z & 3) * NW + (b4.z >> 5)], 1u << (b4.z & 31));
            if ((a4.w >> 2) == bid && a4.w != b4.w)
                atomicOr(&sb[(a4.w & 3) * NW + (b4.w >> 5)], 1u << (b4.w & 31));
        }
        for (int k = (quads << 2) + t; k < E; k += 512) {   // scalar remainder
            const int a = ei[k], b = ei[k + E];
            if ((a >> 2) == bid && a != b)
                atomicOr(&sb[(a & 3) * NW + (b >> 5)], 1u << (b & 31));
        }

        // one matvec per wave: node 4b+(w>>1), xa if (w&1)==0 else xc
        const int v = bid * 4 + (wave >> 1);
        const float* W = (wave & 1) ? W0a : W1a;
        const float xv = x[v * H + lane];
        float a0 = 0, a1 = 0, a2 = 0, a3 = 0;
        #pragma unroll
        for (int k = 0; k < H; k += 4) {
            a0 += __shfl(xv, k, 64)     * W[k * H + lane];
            a1 += __shfl(xv, k + 1, 64) * W[(k + 1) * H + lane];
            a2 += __shfl(xv, k + 2, 64) * W[(k + 2) * H + lane];
            a3 += __shfl(xv, k + 3, 64) * W[(k + 3) * H + lane];
        }
        float r = (a0 + a1) + (a2 + a3);
        if (wave & 1) xc[v * H + lane] = r; else xa[v * H + lane] = r;

        __syncthreads();
        if (t < 4 * NW) bits[(bid * 4 + t / NW) * NWP + (t % NW)] = sb[t];

        // neighbor-list enumeration: waves 0..3 = node bid*4+wave, lanes 0..19
        if (wave < 4) {
            const int n = bid * 4 + wave;
            const unsigned word = (lane < NW) ? sb[wave * NW + lane] : 0u;
            const int pc = __popc(word);
            int scan = pc;
            #pragma unroll
            for (int off = 1; off < 32; off <<= 1) {
                int nb = __shfl_up(scan, off, 64);
                if (lane >= off) scan += nb;
            }
            int o = scan - pc;                          // exclusive prefix
            unsigned c = word;
            while (c) {
                const int b = __ffs(c) - 1; c &= c - 1;
                if (o < MAXD) ulg[n * MAXD + o] = (unsigned short)(lane * 32 + b);
                ++o;
            }
            if (lane == NW - 1) degg[n] = (o < MAXD) ? o : MAXD;
        }
    } else if (bid < 168) {
        const int d = (bid - 160) * 8 + wave;
        const float wv = W1b[d * 65 + lane];          // lane e holds W1b[d][e]
        float a0 = 0, a1 = 0, a2 = 0, a3 = 0;
        #pragma unroll
        for (int e = 0; e < 64; e += 4) {
            a0 += __shfl(wv, e, 64)     * W0a[e * H + lane];
            a1 += __shfl(wv, e + 1, 64) * W0a[(e + 1) * H + lane];
            a2 += __shfl(wv, e + 2, 64) * W0a[(e + 2) * H + lane];
            a3 += __shfl(wv, e + 3, 64) * W0a[(e + 3) * H + lane];
        }
        Wf[d * H + lane] = (a0 + a1) + (a2 + a3) + W1b[d * 65 + 64] * W0a[64 * H + lane];
    } else if (wave == 0) {
        const float bv = b1b[lane];
        float a0 = 0, a1 = 0, a2 = 0, a3 = 0;
        #pragma unroll
        for (int e = 0; e < 64; e += 4) {
            a0 += __shfl(bv, e, 64)     * W0a[e * H + lane];
            a1 += __shfl(bv, e + 1, 64) * W0a[(e + 1) * H + lane];
            a2 += __shfl(bv, e + 2, 64) * W0a[(e + 2) * H + lane];
            a3 += __shfl(bv, e + 3, 64) * W0a[(e + 3) * H + lane];
        }
        bf[lane] = (a0 + a1) + (a2 + a3) + b1b[64] * W0a[64 * H + lane];
    }
}

// ---------------- K2: fused (champion r16) ----------------
// Front: rowv + ulist + deg loaded in ONE parallel round, sync, flat staging
// (pre computed by wave 0 during staging — gates only the pair loop).
__global__ __launch_bounds__(512, 6) void fused(
    const float* __restrict__ xa,  const float* __restrict__ xc,
    const float* __restrict__ W1a, const float* __restrict__ b1a,
    const float* __restrict__ Wf,  const float* __restrict__ bf,
    const float* __restrict__ b0a,
    const float* __restrict__ W0b, const float* __restrict__ b0b,
    const unsigned* __restrict__ bits,
    const unsigned short* __restrict__ ulg, const int* __restrict__ degg,
    float* __restrict__ out)
{
    __shared__ __align__(16) unsigned rowv[NW];
    __shared__ __align__(16) unsigned nbs[MAXD * NW]; // neighbor bit-rows
    __shared__ __align__(4) unsigned short ulist[MAXD];
    __shared__ float xr[MAXD][H];                     // xa rows of N(v)
    __shared__ float p1[8][H];
    __shared__ float p2[8][H];
    __shared__ int pre[NW];
    __shared__ int s_deg;

    const int v = blockIdx.x, t = threadIdx.x;
    const int lane = t & 63, wave = t >> 6;

    // one parallel load round: rowv + ulist words + deg
    if (t < NW) rowv[t] = bits[v * NWP + t];
    if (t >= 64 && t < 64 + MAXD / 2)                 // 48 u32 words of ulist
        ((unsigned*)ulist)[t - 64] = ((const unsigned*)(ulg + v * MAXD))[t - 64];
    if (t == 32) s_deg = degg[v];
    __syncthreads();
    const int deg = s_deg;

    // staging burst (all waves) + pre scan (wave 0, gates only pair loop)
    if (wave == 0) {
        unsigned word = (lane < NW) ? rowv[lane] : 0u;
        int pc = __popc(word), scan = pc;
        #pragma unroll
        for (int off = 1; off < 32; off <<= 1) {
            int nb = __shfl_up(scan, off, 64);
            if (lane >= off) scan += nb;
        }
        if (lane < NW) pre[lane] = scan - pc;         // exclusive prefix
    }
    for (int p = wave; p < deg; p += 8)
        xr[p][lane] = xa[ulist[p] * H + lane];
    for (int idx = t; idx < deg * NW; idx += 512) {
        const int p = idx / NW, w = idx - p * NW;
        nbs[p * NW + w] = bits[ulist[p] * NWP + w];
    }

    const float r64 = W1a[64 * H + lane];
    const float k0  = b1a[lane] + r64;            // b1a + 1*W1a[64]
    const float k1  = r64 + W1a[65 * H + lane];   // per-cnt term

    unsigned rw[NW];
    #pragma unroll
    for (int j = 0; j < NW; ++j) rw[j] = rowv[j];
    __syncthreads();

    float hacc = 0.f;
    for (int p = wave; p < deg; p += 8) {
        const uint4* bu = (const uint4*)(nbs + p * NW);   // 80B rows, 16B-aligned
        const uint4 q0 = bu[0], q1 = bu[1], q2 = bu[2], q3 = bu[3], q4 = bu[4];
        unsigned cw[NW] = {
            rw[0]  & q0.x, rw[1]  & q0.y, rw[2]  & q0.z, rw[3]  & q0.w,
            rw[4]  & q1.x, rw[5]  & q1.y, rw[6]  & q1.z, rw[7]  & q1.w,
            rw[8]  & q2.x, rw[9]  & q2.y, rw[10] & q2.z, rw[11] & q2.w,
            rw[12] & q3.x, rw[13] & q3.y, rw[14] & q3.z, rw[15] & q3.w,
            rw[16] & q4.x, rw[17] & q4.y, rw[18] & q4.z, rw[19] & q4.w };
        int cnt = 0;
        #pragma unroll
        for (int j = 0; j < NW; ++j) cnt += __popc(cw[j]);
        float xs = 0.f;
        #pragma unroll
        for (int j = 0; j < NW; ++j) {
            unsigned c = cw[j];
            while (c) {
                int b = __ffs(c) - 1; c &= c - 1;
                int ps = pre[j] + __popc(rw[j] & ((1u << b) - 1));
                xs += xr[ps][lane];               // common-neighbor xa from LDS
            }
        }
        float h = xr[p][lane] + xs + k0 + (float)cnt * k1;
        hacc += fmaxf(h, 0.f);                    // ReLU then accumulate
    }
    p1[wave][lane] = hacc;
    __syncthreads();

    // tail: h = relu(xc_v + hsum@Wf + deg*bf + b0a); out = h@W0b + b0b
    float hs = 0.f;
    #pragma unroll
    for (int w = 0; w < 8; ++w) hs += p1[w][lane];      // every wave: full hsum
    float s = 0.f;
    #pragma unroll
    for (int i = 0; i < 8; ++i) {
        const int d = wave * 8 + i;
        s += __shfl(hs, d, 64) * Wf[d * H + lane];
    }
    p2[wave][lane] = s;
    __syncthreads();

    float s2 = 0.f;
    #pragma unroll
    for (int w = 0; w < 8; ++w) s2 += p2[w][lane];
    const float hh = fmaxf(xc[v * H + lane] + (float)deg * bf[lane]
                           + b0a[lane] + s2, 0.f);      // full h, every wave
    float o = 0.f;
    #pragma unroll
    for (int i = 0; i < 8; ++i) {
        const int d = wave * 8 + i;
        o += __shfl(hh, d, 64) * W0b[d * H + lane];
    }
    p1[wave][lane] = o;
    __syncthreads();
    if (wave == 0) {
        float oo = b0b[lane];
        #pragma unroll
        for (int w = 0; w < 8; ++w) oo += p1[w][lane];
        out[v * H + lane] = oo;
    }
}

extern "C" void kernel_launch(void* const* d_in, const int* in_sizes, int n_in,
                              void* d_out, int out_size, void* d_ws, size_t ws_size,
                              hipStream_t stream) {
    const float* x   = (const float*)d_in[0];
    const float* W1a = (const float*)d_in[1];
    const float* b1a = (const float*)d_in[2];
    const float* W1b = (const float*)d_in[3];
    const float* b1b = (const float*)d_in[4];
    const float* W0a = (const float*)d_in[5];
    const float* b0a = (const float*)d_in[6];
    const float* W0b = (const float*)d_in[7];
    const float* b0b = (const float*)d_in[8];
    const int*   ei  = (const int*)d_in[9];
    const int    E   = in_sizes[9] / 2;

    char* ws = (char*)d_ws;
    unsigned*       bits = (unsigned*)(ws);                   // 61440 B
    float*          xa   = (float*)(ws + 61440);              // 163840 B
    float*          xc   = (float*)(ws + 61440 + 163840);     // 163840 B
    float*          Wf   = (float*)(ws + 389120);             // 16384 B
    float*          bf   = (float*)(ws + 405504);             // 256 B (pad)
    unsigned short* ulg  = (unsigned short*)(ws + 405888);    // 640*96*2 = 122880 B
    int*            degg = (int*)(ws + 528768);               // 2560 B

    prep<<<169, 512, 0, stream>>>(ei, E, x, W1a, W0a, W1b, b1b,
                                  bits, xa, xc, Wf, bf, ulg, degg);
    fused<<<NN, 512, 0, stream>>>(xa, xc, W1a, b1a, Wf, bf, b0a, W0b, b0b,
                                  bits, ulg, degg, (float*)d_out);
}